// Round 3
// baseline (8519.765 us; speedup 1.0000x reference)
//
#include <hip/hip_runtime.h>
#include <math.h>

#define NN 25000
#define NE 400000

static constexpr float C_S_ = 0.3826834323650898f;   // sin(pi/8)
static constexpr float C_X_ = 0.9238795325112867f;   // cos(pi/8)
static constexpr float Q_   = 0.25f;                 // 1/sqrt(16)
static constexpr float Q_S3 = 0.25f * 0.5773502691896258f; // Q / sqrt(3)

// ---------------- K0: transpose W_fc2 [100][192] -> [192][100] ----------------
__global__ void k_transpose_fc2(const float* __restrict__ Wfc2, float* __restrict__ Wfc2T) {
    int t = blockIdx.x * blockDim.x + threadIdx.x;
    if (t >= 192 * 100) return;
    int o = t / 100, j = t - o * 100;
    Wfc2T[o * 100 + j] = Wfc2[j * 192 + o];
}

// ---------------- K1: node prep -----------------------------------------------
// x1 = attr*(x@W_l1a) + cattr*(x@W_l1c)   (scalars & vectors)
// d_out = C_S * (attr*(x@W_sc_a) + cattr*(x@W_sc_c))   (skip path, added to later)
__global__ __launch_bounds__(256) void k_node_prep(
    const float* __restrict__ ni, const float* __restrict__ attr, const float* __restrict__ cattr,
    const float* __restrict__ Wsa, const float* __restrict__ Wsc,
    const float* __restrict__ Wva, const float* __restrict__ Wvc,
    const float* __restrict__ W1sa, const float* __restrict__ W1sc,
    const float* __restrict__ W1va, const float* __restrict__ W1vc,
    float* __restrict__ x1, float* __restrict__ out)
{
    int t = blockIdx.x * blockDim.x + threadIdx.x;
    if (t >= NN * 160) return;
    int n = t / 160, d = t - n * 160;
    float a = attr[n], c = cattr[n];
    const float* row = ni + (size_t)n * 160;
    float skipv, l1v;
    if (d < 64) {
        float ssa = 0.f, ssc = 0.f, s1a = 0.f, s1c = 0.f;
        #pragma unroll
        for (int k = 0; k < 64; ++k) {
            float x = row[k];
            ssa += x * Wsa[k * 64 + d];
            ssc += x * Wsc[k * 64 + d];
            s1a += x * W1sa[k * 64 + d];
            s1c += x * W1sc[k * 64 + d];
        }
        skipv = a * ssa + c * ssc;
        l1v   = a * s1a + c * s1c;
    } else {
        int idx = d - 64;
        int o = idx / 3, cc = idx - o * 3;
        float ssa = 0.f, ssc = 0.f, s1a = 0.f, s1c = 0.f;
        #pragma unroll
        for (int u = 0; u < 32; ++u) {
            float x = row[64 + u * 3 + cc];
            ssa += x * Wva[u * 32 + o];
            ssc += x * Wvc[u * 32 + o];
            s1a += x * W1va[u * 32 + o];
            s1c += x * W1vc[u * 32 + o];
        }
        skipv = a * ssa + c * ssc;
        l1v   = a * s1a + c * s1c;
    }
    x1[t]  = l1v;
    out[t] = C_S_ * skipv;
}

// ---------------- K2: fused edge MLP + tensor product + atomic scatter --------
__global__ __launch_bounds__(256) void k_edge(
    const float* __restrict__ ele, const float* __restrict__ eattr,
    const int* __restrict__ esrc, const int* __restrict__ edst,
    const float* __restrict__ Wfc1, const float* __restrict__ Wfc2T,
    const float* __restrict__ x1, float* __restrict__ agg)
{
    int e = blockIdx.x * blockDim.x + threadIdx.x;
    if (e >= NE) return;

    float el[10];
    #pragma unroll
    for (int k = 0; k < 10; ++k) el[k] = ele[(size_t)e * 10 + k];

    // hidden layer: h[j] = silu(el . Wfc1[:,j])  -- h lives in registers (static idx)
    float h[100];
    #pragma unroll
    for (int j = 0; j < 100; ++j) {
        float acc = 0.f;
        #pragma unroll
        for (int k = 0; k < 10; ++k) acc += el[k] * Wfc1[k * 100 + j];
        h[j] = acc / (1.f + __expf(-acc));
    }

    int src = esrc[e], dst = edst[e];
    float es  = eattr[(size_t)e * 4 + 0];
    float ev0 = eattr[(size_t)e * 4 + 1];
    float ev1 = eattr[(size_t)e * 4 + 2];
    float ev2 = eattr[(size_t)e * 4 + 3];
    const float* g  = x1 + (size_t)src * 160;
    float*       ag = agg + (size_t)dst * 384;

    // pass A: o in [0,64): w0 -> mid0a, w1 -> mid1a
    for (int o = 0; o < 64; ++o) {
        float w0v = 0.f, w1v = 0.f;
        const float* c0 = Wfc2T + o * 100;
        const float* c1 = Wfc2T + (64 + o) * 100;
        #pragma unroll
        for (int j = 0; j < 100; ++j) {
            float hj = h[j];
            w0v += hj * c0[j];
            w1v += hj * c1[j];
        }
        float gu = g[o];
        atomicAdd(&ag[o], w0v * gu * es * Q_);
        float b = w1v * gu * Q_;
        atomicAdd(&ag[96 + 3 * o + 0], b * ev0);
        atomicAdd(&ag[96 + 3 * o + 1], b * ev1);
        atomicAdd(&ag[96 + 3 * o + 2], b * ev2);
    }
    // pass B: o in [0,32): w2 -> mid1b, w3 -> mid0b
    for (int o = 0; o < 32; ++o) {
        float w2v = 0.f, w3v = 0.f;
        const float* c2 = Wfc2T + (128 + o) * 100;
        const float* c3 = Wfc2T + (160 + o) * 100;
        #pragma unroll
        for (int j = 0; j < 100; ++j) {
            float hj = h[j];
            w2v += hj * c2[j];
            w3v += hj * c3[j];
        }
        float g0 = g[64 + 3 * o + 0];
        float g1 = g[64 + 3 * o + 1];
        float g2 = g[64 + 3 * o + 2];
        float b = w2v * es * Q_;
        atomicAdd(&ag[288 + 3 * o + 0], b * g0);
        atomicAdd(&ag[288 + 3 * o + 1], b * g1);
        atomicAdd(&ag[288 + 3 * o + 2], b * g2);
        float dg = g0 * ev0 + g1 * ev1 + g2 * ev2;
        atomicAdd(&ag[64 + o], w3v * dg * Q_S3);
    }
}

// ---------------- K3a: l2 FCTP pair -------------------------------------------
__global__ __launch_bounds__(256) void k_l2(
    const float* __restrict__ agg, const float* __restrict__ attr, const float* __restrict__ cattr,
    const float* __restrict__ Wsa, const float* __restrict__ Wsc,
    const float* __restrict__ Wva, const float* __restrict__ Wvc,
    float* __restrict__ l2o)
{
    int t = blockIdx.x * blockDim.x + threadIdx.x;
    if (t >= NN * 384) return;
    int n = t / 384, d = t - n * 384;
    float a = attr[n], c = cattr[n];
    const float* m = agg + (size_t)n * 384;
    float va = 0.f, vc = 0.f;
    if (d < 96) {
        #pragma unroll 8
        for (int k = 0; k < 96; ++k) {
            float x = m[k];
            va += x * Wsa[k * 96 + d];
            vc += x * Wsc[k * 96 + d];
        }
    } else {
        int idx = d - 96;
        int o = idx / 3, cc = idx - o * 3;
        #pragma unroll 8
        for (int u = 0; u < 96; ++u) {
            float x = m[96 + u * 3 + cc];
            va += x * Wva[u * 96 + o];
            vc += x * Wvc[u * 96 + o];
        }
    }
    l2o[t] = a * va + c * vc;
}

// ---------------- K3b: l3 FCTP + final combine --------------------------------
__global__ __launch_bounds__(256) void k_l3(
    const float* __restrict__ l2o, const float* __restrict__ sym,
    const float* __restrict__ Wl3s, const float* __restrict__ Wl3v,
    float* __restrict__ out)
{
    int t = blockIdx.x * blockDim.x + threadIdx.x;
    if (t >= NN * 160) return;
    int n = t / 160, d = t - n * 160;
    float s = sym[n];
    const float* m = l2o + (size_t)n * 384;
    float acc = 0.f;
    if (d < 64) {
        #pragma unroll 8
        for (int k = 0; k < 96; ++k) acc += m[k] * Wl3s[k * 64 + d];
    } else {
        int idx = d - 64;
        int o = idx / 3, cc = idx - o * 3;
        #pragma unroll 8
        for (int u = 0; u < 96; ++u) acc += m[96 + u * 3 + cc] * Wl3v[u * 32 + o];
    }
    out[t] = out[t] + C_X_ * s * acc;
}

extern "C" void kernel_launch(void* const* d_in, const int* in_sizes, int n_in,
                              void* d_out, int out_size, void* d_ws, size_t ws_size,
                              hipStream_t stream) {
    const float* ni    = (const float*)d_in[0];
    const float* attr  = (const float*)d_in[1];
    const float* cattr = (const float*)d_in[2];
    const float* sym   = (const float*)d_in[3];
    const float* eattr = (const float*)d_in[4];
    const float* ele   = (const float*)d_in[5];
    const int*   esrc  = (const int*)d_in[6];
    const int*   edst  = (const int*)d_in[7];
    const float* Ws_sc_a = (const float*)d_in[8];
    const float* Wv_sc_a = (const float*)d_in[9];
    const float* Ws_sc_c = (const float*)d_in[10];
    const float* Wv_sc_c = (const float*)d_in[11];
    const float* Ws_l1_a = (const float*)d_in[12];
    const float* Wv_l1_a = (const float*)d_in[13];
    const float* Ws_l1_c = (const float*)d_in[14];
    const float* Wv_l1_c = (const float*)d_in[15];
    const float* Wfc1    = (const float*)d_in[16];
    const float* Wfc2    = (const float*)d_in[17];
    const float* Ws_l2_a = (const float*)d_in[18];
    const float* Wv_l2_a = (const float*)d_in[19];
    const float* Ws_l2_c = (const float*)d_in[20];
    const float* Wv_l2_c = (const float*)d_in[21];
    const float* Ws_l3   = (const float*)d_in[22];
    const float* Wv_l3   = (const float*)d_in[23];

    float* out = (float*)d_out;
    float* ws  = (float*)d_ws;
    float* x1    = ws;                      // NN*160   = 4,000,000 floats
    float* agg   = x1  + (size_t)NN * 160;  // NN*384   = 9,600,000 floats
    float* l2o   = agg + (size_t)NN * 384;  // NN*384   = 9,600,000 floats
    float* Wfc2T = l2o + (size_t)NN * 384;  // 192*100  = 19,200 floats

    // ws budget check: 23,219,200 floats = 92,876,800 B. If d_ws is smaller,
    // bail out cleanly (output stays zero -> absmax ~= 22.125 tells us this
    // branch was taken) instead of corrupting memory / wedging the GPU.
    size_t need_bytes = ((size_t)NN * 160 + (size_t)NN * 384 * 2 + 192 * 100) * sizeof(float);
    if (ws_size < need_bytes) return;

    hipMemsetAsync(agg, 0, (size_t)NN * 384 * sizeof(float), stream);

    k_transpose_fc2<<<(192 * 100 + 255) / 256, 256, 0, stream>>>(Wfc2, Wfc2T);

    k_node_prep<<<(NN * 160 + 255) / 256, 256, 0, stream>>>(
        ni, attr, cattr,
        Ws_sc_a, Ws_sc_c, Wv_sc_a, Wv_sc_c,
        Ws_l1_a, Ws_l1_c, Wv_l1_a, Wv_l1_c,
        x1, out);

    k_edge<<<(NE + 255) / 256, 256, 0, stream>>>(
        ele, eattr, esrc, edst, Wfc1, Wfc2T, x1, agg);

    k_l2<<<(NN * 384 + 255) / 256, 256, 0, stream>>>(
        agg, attr, cattr, Ws_l2_a, Ws_l2_c, Wv_l2_a, Wv_l2_c, l2o);

    k_l3<<<(NN * 160 + 255) / 256, 256, 0, stream>>>(
        l2o, sym, Ws_l3, Wv_l3, out);
}

// Round 4
// 1566.168 us; speedup vs baseline: 5.4399x; 5.4399x over previous
//
#include <hip/hip_runtime.h>
#include <math.h>

#define NN 25000
#define NE 400000

static constexpr float C_S_ = 0.3826834323650898f;   // sin(pi/8)
static constexpr float C_X_ = 0.9238795325112867f;   // cos(pi/8)
static constexpr float Q_   = 0.25f;                 // 1/sqrt(16)
static constexpr float Q_S3 = 0.25f * 0.5773502691896258f; // Q / sqrt(3)

__device__ inline unsigned short f2bf(float f) {
    union { float f; unsigned u; } v; v.f = f;
    unsigned r = v.u + 0x7fffu + ((v.u >> 16) & 1u);   // RNE
    return (unsigned short)(r >> 16);
}
__device__ inline float bf2f(unsigned short s) {
    union { unsigned u; float f; } v; v.u = ((unsigned)s) << 16;
    return v.f;
}

// ---------------- K0: transpose W_fc2 [100][192] -> [192][100] ----------------
__global__ void k_transpose_fc2(const float* __restrict__ Wfc2, float* __restrict__ Wfc2T) {
    int t = blockIdx.x * blockDim.x + threadIdx.x;
    if (t >= 192 * 100) return;
    int o = t / 100, j = t - o * 100;
    Wfc2T[o * 100 + j] = Wfc2[j * 192 + o];
}

// ---------------- K1: node prep -----------------------------------------------
__global__ __launch_bounds__(256) void k_node_prep(
    const float* __restrict__ ni, const float* __restrict__ attr, const float* __restrict__ cattr,
    const float* __restrict__ Wsa, const float* __restrict__ Wsc,
    const float* __restrict__ Wva, const float* __restrict__ Wvc,
    const float* __restrict__ W1sa, const float* __restrict__ W1sc,
    const float* __restrict__ W1va, const float* __restrict__ W1vc,
    float* __restrict__ x1, float* __restrict__ out)
{
    int t = blockIdx.x * blockDim.x + threadIdx.x;
    if (t >= NN * 160) return;
    int n = t / 160, d = t - n * 160;
    float a = attr[n], c = cattr[n];
    const float* row = ni + (size_t)n * 160;
    float skipv, l1v;
    if (d < 64) {
        float ssa = 0.f, ssc = 0.f, s1a = 0.f, s1c = 0.f;
        #pragma unroll
        for (int k = 0; k < 64; ++k) {
            float x = row[k];
            ssa += x * Wsa[k * 64 + d];
            ssc += x * Wsc[k * 64 + d];
            s1a += x * W1sa[k * 64 + d];
            s1c += x * W1sc[k * 64 + d];
        }
        skipv = a * ssa + c * ssc;
        l1v   = a * s1a + c * s1c;
    } else {
        int idx = d - 64;
        int o = idx / 3, cc = idx - o * 3;
        float ssa = 0.f, ssc = 0.f, s1a = 0.f, s1c = 0.f;
        #pragma unroll
        for (int u = 0; u < 32; ++u) {
            float x = row[64 + u * 3 + cc];
            ssa += x * Wva[u * 32 + o];
            ssc += x * Wvc[u * 32 + o];
            s1a += x * W1va[u * 32 + o];
            s1c += x * W1vc[u * 32 + o];
        }
        skipv = a * ssa + c * ssc;
        l1v   = a * s1a + c * s1c;
    }
    x1[t]  = l1v;
    out[t] = C_S_ * skipv;
}

// ---------------- sort: histogram ---------------------------------------------
__global__ __launch_bounds__(256) void k_hist(const int* __restrict__ edst, int* __restrict__ cnt) {
    int e = blockIdx.x * blockDim.x + threadIdx.x;
    if (e >= NE) return;
    atomicAdd(&cnt[edst[e]], 1);
}

// ---------------- sort: single-block exclusive scan over NN counts ------------
__global__ __launch_bounds__(1024) void k_scan(const int* __restrict__ cnt,
                                               int* __restrict__ start, int* __restrict__ cursor) {
    __shared__ int wsum[16];
    __shared__ int carry_s;
    int lane = threadIdx.x & 63, wid = threadIdx.x >> 6;
    if (threadIdx.x == 0) carry_s = 0;
    __syncthreads();
    for (int base = 0; base < NN; base += 1024) {
        int i = base + threadIdx.x;
        int v = (i < NN) ? cnt[i] : 0;
        int x = v;
        #pragma unroll
        for (int off = 1; off < 64; off <<= 1) {
            int y = __shfl_up(x, off, 64);
            if (lane >= off) x += y;
        }
        if (lane == 63) wsum[wid] = x;
        __syncthreads();
        if (wid == 0 && lane < 16) {
            int s = wsum[lane];
            #pragma unroll
            for (int off = 1; off < 16; off <<= 1) {
                int y = __shfl_up(s, off, 64);
                if (lane >= off) s += y;
            }
            wsum[lane] = s;            // inclusive scan of wave sums
        }
        __syncthreads();
        int woff = (wid > 0) ? wsum[wid - 1] : 0;
        int excl = x - v + woff + carry_s;
        if (i < NN) { start[i] = excl; cursor[i] = excl; }
        __syncthreads();
        if (threadIdx.x == 1023) carry_s += wsum[15];
        __syncthreads();
    }
    if (threadIdx.x == 0) start[NN] = NE;
}

// ---------------- sort: scatter edge ids --------------------------------------
__global__ __launch_bounds__(256) void k_scatter(const int* __restrict__ edst,
                                                 int* __restrict__ cursor,
                                                 int* __restrict__ sorted, int* __restrict__ pos_arr) {
    int e = blockIdx.x * blockDim.x + threadIdx.x;
    if (e >= NE) return;
    int p = atomicAdd(&cursor[edst[e]], 1);
    sorted[p] = e;
    pos_arr[e] = p;
}

// ---------------- K2a: edge MLP -> 192 bf16 weights (stored in sorted order) --
__global__ __launch_bounds__(256) void k_edgew(
    const float* __restrict__ ele,
    const float* __restrict__ Wfc1, const float* __restrict__ Wfc2T,
    const int* __restrict__ pos_arr, unsigned short* __restrict__ wbuf)
{
    int e = blockIdx.x * blockDim.x + threadIdx.x;
    if (e >= NE) return;

    float el[10];
    #pragma unroll
    for (int k = 0; k < 10; ++k) el[k] = ele[(size_t)e * 10 + k];

    float h[100];
    #pragma unroll
    for (int j = 0; j < 100; ++j) {
        float acc = 0.f;
        #pragma unroll
        for (int k = 0; k < 10; ++k) acc += el[k] * Wfc1[k * 100 + j];
        h[j] = acc / (1.f + __expf(-acc));
    }

    unsigned short* wrow = wbuf + (size_t)pos_arr[e] * 192;

    // pass A: w0 (->[0,64)) and w1 (->[64,128)), unroll 2 for packed stores
    for (int o = 0; o < 64; o += 2) {
        float w0a = 0.f, w0b = 0.f, w1a = 0.f, w1b = 0.f;
        const float* c0a = Wfc2T + o * 100;        const float* c0b = c0a + 100;
        const float* c1a = Wfc2T + (64 + o) * 100; const float* c1b = c1a + 100;
        #pragma unroll
        for (int j = 0; j < 100; ++j) {
            float hj = h[j];
            w0a += hj * c0a[j]; w0b += hj * c0b[j];
            w1a += hj * c1a[j]; w1b += hj * c1b[j];
        }
        *(unsigned int*)&wrow[o]      = (unsigned)f2bf(w0a) | ((unsigned)f2bf(w0b) << 16);
        *(unsigned int*)&wrow[64 + o] = (unsigned)f2bf(w1a) | ((unsigned)f2bf(w1b) << 16);
    }
    // pass B: w2 (->[128,160)) and w3 (->[160,192))
    for (int o = 0; o < 32; o += 2) {
        float w2a = 0.f, w2b = 0.f, w3a = 0.f, w3b = 0.f;
        const float* c2a = Wfc2T + (128 + o) * 100; const float* c2b = c2a + 100;
        const float* c3a = Wfc2T + (160 + o) * 100; const float* c3b = c3a + 100;
        #pragma unroll
        for (int j = 0; j < 100; ++j) {
            float hj = h[j];
            w2a += hj * c2a[j]; w2b += hj * c2b[j];
            w3a += hj * c3a[j]; w3b += hj * c3b[j];
        }
        *(unsigned int*)&wrow[128 + o] = (unsigned)f2bf(w2a) | ((unsigned)f2bf(w2b) << 16);
        *(unsigned int*)&wrow[160 + o] = (unsigned)f2bf(w3a) | ((unsigned)f2bf(w3b) << 16);
    }
}

// ---------------- K2b: per-node gather + TP accumulate (no atomics) -----------
__global__ __launch_bounds__(384) void k_gather(
    const int* __restrict__ start, const int* __restrict__ sorted,
    const int* __restrict__ esrc, const float* __restrict__ eattr,
    const unsigned short* __restrict__ wbuf, const float* __restrict__ x1,
    float* __restrict__ agg)
{
    int n = blockIdx.x;
    int t = threadIdx.x;
    int s0 = start[n], s1 = start[n + 1];

    // per-thread output-feature mapping (loop invariant)
    int widx, gidx, kind, csel = 0;
    float scale;
    if (t < 64)       { widx = t;                gidx = t;              kind = 0; scale = Q_;   }
    else if (t < 96)  { int o = t - 64;          widx = 160 + o; gidx = 64 + 3 * o; kind = 1; scale = Q_S3; }
    else if (t < 288) { int idx = t - 96; int u = idx / 3; csel = idx - 3 * u;
                        widx = 64 + u;           gidx = u;              kind = 2; scale = Q_;   }
    else              { int idx = t - 288; int o = idx / 3; int c = idx - 3 * o;
                        widx = 128 + o;          gidx = 64 + 3 * o + c; kind = 0; scale = Q_;   }

    float acc = 0.f;
    for (int i = s0; i < s1; ++i) {
        int e = sorted[i];
        int src = esrc[e];
        float4 ea = *(const float4*)(eattr + (size_t)e * 4);   // es, ev0, ev1, ev2
        const float* g = x1 + (size_t)src * 160;
        float wv = bf2f(wbuf[(size_t)i * 192 + widx]);
        float contrib;
        if (kind == 0)      contrib = wv * g[gidx] * ea.x;
        else if (kind == 1) contrib = wv * (g[gidx] * ea.y + g[gidx + 1] * ea.z + g[gidx + 2] * ea.w);
        else {
            float evc = (csel == 0) ? ea.y : ((csel == 1) ? ea.z : ea.w);
            contrib = wv * g[gidx] * evc;
        }
        acc += contrib;
    }
    agg[(size_t)n * 384 + t] = acc * scale;
}

// ---------------- fallback K2: fused edge + atomic scatter (known-good) -------
__global__ __launch_bounds__(256) void k_edge(
    const float* __restrict__ ele, const float* __restrict__ eattr,
    const int* __restrict__ esrc, const int* __restrict__ edst,
    const float* __restrict__ Wfc1, const float* __restrict__ Wfc2T,
    const float* __restrict__ x1, float* __restrict__ agg)
{
    int e = blockIdx.x * blockDim.x + threadIdx.x;
    if (e >= NE) return;
    float el[10];
    #pragma unroll
    for (int k = 0; k < 10; ++k) el[k] = ele[(size_t)e * 10 + k];
    float h[100];
    #pragma unroll
    for (int j = 0; j < 100; ++j) {
        float acc = 0.f;
        #pragma unroll
        for (int k = 0; k < 10; ++k) acc += el[k] * Wfc1[k * 100 + j];
        h[j] = acc / (1.f + __expf(-acc));
    }
    int src = esrc[e], dst = edst[e];
    float es  = eattr[(size_t)e * 4 + 0];
    float ev0 = eattr[(size_t)e * 4 + 1];
    float ev1 = eattr[(size_t)e * 4 + 2];
    float ev2 = eattr[(size_t)e * 4 + 3];
    const float* g  = x1 + (size_t)src * 160;
    float*       ag = agg + (size_t)dst * 384;
    for (int o = 0; o < 64; ++o) {
        float w0v = 0.f, w1v = 0.f;
        const float* c0 = Wfc2T + o * 100;
        const float* c1 = Wfc2T + (64 + o) * 100;
        #pragma unroll
        for (int j = 0; j < 100; ++j) { float hj = h[j]; w0v += hj * c0[j]; w1v += hj * c1[j]; }
        float gu = g[o];
        atomicAdd(&ag[o], w0v * gu * es * Q_);
        float b = w1v * gu * Q_;
        atomicAdd(&ag[96 + 3 * o + 0], b * ev0);
        atomicAdd(&ag[96 + 3 * o + 1], b * ev1);
        atomicAdd(&ag[96 + 3 * o + 2], b * ev2);
    }
    for (int o = 0; o < 32; ++o) {
        float w2v = 0.f, w3v = 0.f;
        const float* c2 = Wfc2T + (128 + o) * 100;
        const float* c3 = Wfc2T + (160 + o) * 100;
        #pragma unroll
        for (int j = 0; j < 100; ++j) { float hj = h[j]; w2v += hj * c2[j]; w3v += hj * c3[j]; }
        float g0 = g[64 + 3 * o + 0];
        float g1 = g[64 + 3 * o + 1];
        float g2 = g[64 + 3 * o + 2];
        float b = w2v * es * Q_;
        atomicAdd(&ag[288 + 3 * o + 0], b * g0);
        atomicAdd(&ag[288 + 3 * o + 1], b * g1);
        atomicAdd(&ag[288 + 3 * o + 2], b * g2);
        float dg = g0 * ev0 + g1 * ev1 + g2 * ev2;
        atomicAdd(&ag[64 + o], w3v * dg * Q_S3);
    }
}

// ---------------- K3a: l2 FCTP pair -------------------------------------------
__global__ __launch_bounds__(256) void k_l2(
    const float* __restrict__ agg, const float* __restrict__ attr, const float* __restrict__ cattr,
    const float* __restrict__ Wsa, const float* __restrict__ Wsc,
    const float* __restrict__ Wva, const float* __restrict__ Wvc,
    float* __restrict__ l2o)
{
    int t = blockIdx.x * blockDim.x + threadIdx.x;
    if (t >= NN * 384) return;
    int n = t / 384, d = t - n * 384;
    float a = attr[n], c = cattr[n];
    const float* m = agg + (size_t)n * 384;
    float va = 0.f, vc = 0.f;
    if (d < 96) {
        #pragma unroll 8
        for (int k = 0; k < 96; ++k) {
            float x = m[k];
            va += x * Wsa[k * 96 + d];
            vc += x * Wsc[k * 96 + d];
        }
    } else {
        int idx = d - 96;
        int o = idx / 3, cc = idx - o * 3;
        #pragma unroll 8
        for (int u = 0; u < 96; ++u) {
            float x = m[96 + u * 3 + cc];
            va += x * Wva[u * 96 + o];
            vc += x * Wvc[u * 96 + o];
        }
    }
    l2o[t] = a * va + c * vc;
}

// ---------------- K3b: l3 FCTP + final combine --------------------------------
__global__ __launch_bounds__(256) void k_l3(
    const float* __restrict__ l2o, const float* __restrict__ sym,
    const float* __restrict__ Wl3s, const float* __restrict__ Wl3v,
    float* __restrict__ out)
{
    int t = blockIdx.x * blockDim.x + threadIdx.x;
    if (t >= NN * 160) return;
    int n = t / 160, d = t - n * 160;
    float s = sym[n];
    const float* m = l2o + (size_t)n * 384;
    float acc = 0.f;
    if (d < 64) {
        #pragma unroll 8
        for (int k = 0; k < 96; ++k) acc += m[k] * Wl3s[k * 64 + d];
    } else {
        int idx = d - 64;
        int o = idx / 3, cc = idx - o * 3;
        #pragma unroll 8
        for (int u = 0; u < 96; ++u) acc += m[96 + u * 3 + cc] * Wl3v[u * 32 + o];
    }
    out[t] = out[t] + C_X_ * s * acc;
}

extern "C" void kernel_launch(void* const* d_in, const int* in_sizes, int n_in,
                              void* d_out, int out_size, void* d_ws, size_t ws_size,
                              hipStream_t stream) {
    const float* ni    = (const float*)d_in[0];
    const float* attr  = (const float*)d_in[1];
    const float* cattr = (const float*)d_in[2];
    const float* sym   = (const float*)d_in[3];
    const float* eattr = (const float*)d_in[4];
    const float* ele   = (const float*)d_in[5];
    const int*   esrc  = (const int*)d_in[6];
    const int*   edst  = (const int*)d_in[7];
    const float* Ws_sc_a = (const float*)d_in[8];
    const float* Wv_sc_a = (const float*)d_in[9];
    const float* Ws_sc_c = (const float*)d_in[10];
    const float* Wv_sc_c = (const float*)d_in[11];
    const float* Ws_l1_a = (const float*)d_in[12];
    const float* Wv_l1_a = (const float*)d_in[13];
    const float* Ws_l1_c = (const float*)d_in[14];
    const float* Wv_l1_c = (const float*)d_in[15];
    const float* Wfc1    = (const float*)d_in[16];
    const float* Wfc2    = (const float*)d_in[17];
    const float* Ws_l2_a = (const float*)d_in[18];
    const float* Wv_l2_a = (const float*)d_in[19];
    const float* Ws_l2_c = (const float*)d_in[20];
    const float* Wv_l2_c = (const float*)d_in[21];
    const float* Ws_l3   = (const float*)d_in[22];
    const float* Wv_l3   = (const float*)d_in[23];

    float* out = (float*)d_out;
    float* ws  = (float*)d_ws;
    float* x1    = ws;                       // NN*160
    float* agg   = x1  + (size_t)NN * 160;   // NN*384
    float* l2o   = agg + (size_t)NN * 384;   // NN*384
    float* Wfc2T = l2o + (size_t)NN * 384;   // 192*100

    size_t need_base = ((size_t)NN * 160 + (size_t)NN * 384 * 2 + 192 * 100) * sizeof(float);
    if (ws_size < need_base) return;   // can't run at all (absmax ~22 signals this)

    // fast-path extra buffers
    unsigned short* wbuf   = (unsigned short*)(Wfc2T + 192 * 100);  // NE*192 bf16
    int* cnt     = (int*)(wbuf + (size_t)NE * 192);                 // NN
    int* start_  = cnt + NN;                                        // NN+1
    int* cursor  = start_ + NN + 1;                                 // NN
    int* pos_arr = cursor + NN;                                     // NE
    int* sorted  = pos_arr + NE;                                    // NE
    size_t need_fast = need_base + (size_t)NE * 192 * 2
                     + ((size_t)NN * 3 + 1 + (size_t)NE * 2) * sizeof(int);
    bool fast = (ws_size >= need_fast);

    k_transpose_fc2<<<(192 * 100 + 255) / 256, 256, 0, stream>>>(Wfc2, Wfc2T);

    k_node_prep<<<(NN * 160 + 255) / 256, 256, 0, stream>>>(
        ni, attr, cattr,
        Ws_sc_a, Ws_sc_c, Wv_sc_a, Wv_sc_c,
        Ws_l1_a, Ws_l1_c, Wv_l1_a, Wv_l1_c,
        x1, out);

    if (fast) {
        hipMemsetAsync(cnt, 0, (size_t)NN * sizeof(int), stream);
        k_hist<<<(NE + 255) / 256, 256, 0, stream>>>(edst, cnt);
        k_scan<<<1, 1024, 0, stream>>>(cnt, start_, cursor);
        k_scatter<<<(NE + 255) / 256, 256, 0, stream>>>(edst, cursor, sorted, pos_arr);
        k_edgew<<<(NE + 255) / 256, 256, 0, stream>>>(ele, Wfc1, Wfc2T, pos_arr, wbuf);
        k_gather<<<NN, 384, 0, stream>>>(start_, sorted, esrc, eattr, wbuf, x1, agg);
    } else {
        hipMemsetAsync(agg, 0, (size_t)NN * 384 * sizeof(float), stream);
        k_edge<<<(NE + 255) / 256, 256, 0, stream>>>(
            ele, eattr, esrc, edst, Wfc1, Wfc2T, x1, agg);
    }

    k_l2<<<(NN * 384 + 255) / 256, 256, 0, stream>>>(
        agg, attr, cattr, Ws_l2_a, Ws_l2_c, Wv_l2_a, Wv_l2_c, l2o);

    k_l3<<<(NN * 160 + 255) / 256, 256, 0, stream>>>(
        l2o, sym, Ws_l3, Wv_l3, out);
}